// Round 1
// baseline (138.275 us; speedup 1.0000x reference)
//
#include <hip/hip_runtime.h>
#include <hip/hip_bf16.h>

// LoRA-factored 3x3 conv. out fp32. Input dtypes runtime-detected.
// x: [16,128,56,56], A: [256,16], B: [16,1152] -> out: [16,256,56,56]
// R5: shifted-accumulator trick — each lane loads ONLY its own pixel x[w];
// three acc sets (dw=-1,0,1) recombined once at the end via __shfl. Kills
// per-tap cndmask/addr VALU and cuts loads 3x. 512-thr blocks (8 waves =
// 4 ch-slices x 2 rank-halves), 4 blocks/CU -> 896 blocks all resident in
// ONE round (no tail).

#define Bn 16
#define Cc 128
#define Hh 56
#define Ww 56
#define Ll (Hh * Ww)      // 3136
#define Rr 16
#define Oo 256
#define KF (Cc * 9)       // 1152

__device__ __forceinline__ float bf16_bits(unsigned short u) {
    return __uint_as_float(((unsigned)u) << 16);
}

template<bool BF>
__device__ __forceinline__ float ld(const void* __restrict__ p, size_t i) {
    if constexpr (BF) return bf16_bits(((const unsigned short*)p)[i]);
    else              return ((const float*)p)[i];
}

// bf16-packed: bits14..7 of each dword = a bf16 exponent (~[96,144]) -> 32/32.
// fp32: uniform mantissa bits -> ~6/32. Threshold 20. (Proven R3.)
__device__ __forceinline__ bool detect_bf16(const void* __restrict__ p) {
    const unsigned* w = (const unsigned*)p;
    int c = 0;
#pragma unroll
    for (int i = 0; i < 32; ++i) {
        const unsigned e = (w[i] >> 7) & 0xFFu;
        c += (e >= 96u && e <= 144u) ? 1 : 0;
    }
    return c >= 20;
}

// ---- prep: Bt[k][r] = B[r][k] as fp32 (k = c*9+i), Afp[o][r] = A[o][r] fp32.
__global__ __launch_bounds__(256) void prep_kernel(
    const void* __restrict__ A, const void* __restrict__ Bm,
    float* __restrict__ Bt, float* __restrict__ Afp)
{
    const bool ab = detect_bf16(A);
    const bool bb = detect_bf16(Bm);
    const int i = blockIdx.x * 256 + threadIdx.x;
    if (i < KF * Rr) {
        const int k = i >> 4, r = i & 15;
        Bt[i] = bb ? bf16_bits(((const unsigned short*)Bm)[r * KF + k])
                   : ((const float*)Bm)[r * KF + k];
    }
    if (i < Oo * Rr) {
        Afp[i] = ab ? bf16_bits(((const unsigned short*)A)[i])
                    : ((const float*)A)[i];
    }
}

// ---- main: one block = one (b, h) row. 8 waves = 4 channel-slices x 2 rank-halves.
template<bool XB>
__device__ __forceinline__ void main_body(
    const void* __restrict__ x,
    const float* __restrict__ Bt,
    const float* __restrict__ Afp,
    float* __restrict__ out,
    float (* __restrict__ part)[Rr][64],   // [4][16][64]
    float (* __restrict__ tmp2)[17])       // [64][17]
{
    const int tid  = threadIdx.x;
    const int lane = tid & 63;                                  // w coordinate
    const int wv   = __builtin_amdgcn_readfirstlane(tid >> 6);  // wave 0..7 (SGPR)
    const int cs   = wv & 3;    // channel slice: channels cs*32 .. +32
    const int rh   = wv >> 2;   // rank half: ranks rh*8 .. +8
    const int h    = blockIdx.x;
    const int b    = blockIdx.y;
    const int w    = lane;
    const bool wok = (w < Ww);
    const int  wcl = wok ? w : (Ww - 1);   // clamp lanes 56..63 (garbage, masked)

    // a0/a1/a2: accumulators for dw = 0,1,2 taps, each over 8 ranks.
    float a0[8], a1[8], a2[8];
#pragma unroll
    for (int j = 0; j < 8; ++j) { a0[j] = 0.f; a1[j] = 0.f; a2[j] = 0.f; }

    const size_t xbase = (size_t)b * Cc * Ll + (size_t)(cs * 32) * Ll;
    const float* btb   = Bt + (size_t)(cs * 32 * 9) * Rr + rh * 8;

    // h-bounds are wave-uniform -> scalar branch, hoisted out of channel loop.
#pragma unroll
    for (int dh = 0; dh < 3; ++dh) {
        const int hh = h + dh - 1;
        if (hh >= 0 && hh < Hh) {
            const size_t rowoff = xbase + (size_t)(hh * Ww) + (size_t)wcl;
#pragma unroll 4
            for (int cc = 0; cc < 32; ++cc) {
                // uniform SGPR base + constant lane offset: zero per-lane addr math
                const float xv = ld<XB>(x, rowoff + (size_t)cc * Ll);
                const float* bt = btb + (size_t)(cc * 9 + dh * 3) * Rr;
#pragma unroll
                for (int j = 0; j < 8; ++j) a0[j] += bt[j]          * xv;
#pragma unroll
                for (int j = 0; j < 8; ++j) a1[j] += bt[Rr + j]     * xv;
#pragma unroll
                for (int j = 0; j < 8; ++j) a2[j] += bt[2 * Rr + j] * xv;
            }
        }
    }

    // horizontal recombine (once): out[w] = a1[w] + a0[w-1] + a2[w+1]
    // lane 0's a0 source and lane>=55's a2 source are padding -> masked to 0.
#pragma unroll
    for (int j = 0; j < 8; ++j) {
        const float up = __shfl(a0[j], w - 1);
        const float dn = __shfl(a2[j], w + 1);
        float s = a1[j];
        s += (w > 0)      ? up : 0.f;
        s += (w < Ww - 1) ? dn : 0.f;
        part[cs][rh * 8 + j][lane] = s;
    }
    __syncthreads();

    // cross-wave reduction: 4 channel-slices -> tmp2[px][r]
    {
        const int rr = tid >> 6;    // 0..7
        const int px = tid & 63;
#pragma unroll
        for (int t = 0; t < 2; ++t) {
            const int r = rr + t * 8;
            const float s = part[0][r][px] + part[1][r][px]
                          + part[2][r][px] + part[3][r][px];
            tmp2[px][r] = s;        // stride 17 -> conflict-free
        }
    }
    __syncthreads();

    // stage 2: wave wv emits output channels wv*32 .. +32
    float tv[Rr];
#pragma unroll
    for (int r = 0; r < Rr; ++r) tv[r] = tmp2[lane][r];

    const size_t obase = (size_t)b * Oo * Ll + (size_t)(h * Ww) + (size_t)w;
#pragma unroll 4
    for (int j = 0; j < 32; ++j) {
        const int o = wv * 32 + j;
        const float* Ao = Afp + (size_t)o * Rr;   // uniform -> s_load
        float s = 0.f;
#pragma unroll
        for (int r = 0; r < Rr; ++r) s += Ao[r] * tv[r];
        if (wok) out[obase + (size_t)o * Ll] = s;
    }
}

__global__ __launch_bounds__(512, 8) void fused_big(
    const void* __restrict__ x,
    const float* __restrict__ Bt,
    const float* __restrict__ Afp,
    float* __restrict__ out)
{
    __shared__ float part[4][Rr][64];   // 16 KB
    __shared__ float tmp2[64][17];      // 4.3 KB
    if (detect_bf16(x)) main_body<true >(x, Bt, Afp, out, part, tmp2);
    else                main_body<false>(x, Bt, Afp, out, part, tmp2);
}

// ---- fallback (ws too small): slow but correct, no workspace.
__global__ __launch_bounds__(256) void fused_fallback(
    const void* __restrict__ x, const void* __restrict__ A,
    const void* __restrict__ Bm, float* __restrict__ out)
{
    const bool xb = detect_bf16(x);
    const bool ab = detect_bf16(A);
    const bool bb = detect_bf16(Bm);
    const int gid = blockIdx.x * 256 + threadIdx.x;
    const int b = gid / Ll;
    const int l = gid - b * Ll;
    const int h = l / Ww, w = l - h * Ww;
    float acc[Rr];
#pragma unroll
    for (int r = 0; r < Rr; ++r) acc[r] = 0.f;
    const size_t xbase = (size_t)b * Cc * Ll;
    for (int c = 0; c < Cc; ++c) {
        const size_t xc = xbase + (size_t)c * Ll;
        float xv[9];
#pragma unroll
        for (int dh = 0; dh < 3; ++dh) {
            const int hh = h + dh - 1;
            const bool hok = (hh >= 0) & (hh < Hh);
#pragma unroll
            for (int dw = 0; dw < 3; ++dw) {
                const int ww = w + dw - 1;
                const bool ok = hok & (ww >= 0) & (ww < Ww);
                const size_t idx = xc + (size_t)(hh * Ww + ww);
                xv[dh*3+dw] = ok ? (xb ? bf16_bits(((const unsigned short*)x)[idx])
                                       : ((const float*)x)[idx]) : 0.f;
            }
        }
#pragma unroll
        for (int r = 0; r < Rr; ++r) {
            const size_t bo = (size_t)r * KF + (size_t)c * 9;
            float s = acc[r];
#pragma unroll
            for (int i = 0; i < 9; ++i)
                s += (bb ? bf16_bits(((const unsigned short*)Bm)[bo+i])
                         : ((const float*)Bm)[bo+i]) * xv[i];
            acc[r] = s;
        }
    }
    const size_t obase = (size_t)b * Oo * Ll + (size_t)l;
    for (int o = 0; o < Oo; ++o) {
        float s = 0.f;
#pragma unroll
        for (int r = 0; r < Rr; ++r)
            s += (ab ? bf16_bits(((const unsigned short*)A)[o*Rr+r])
                     : ((const float*)A)[o*Rr+r]) * acc[r];
        out[obase + (size_t)o * Ll] = s;
    }
}

extern "C" void kernel_launch(void* const* d_in, const int* in_sizes, int n_in,
                              void* d_out, int out_size, void* d_ws, size_t ws_size,
                              hipStream_t stream) {
    const void* x  = d_in[0];
    const void* A  = d_in[1];
    const void* Bm = d_in[2];
    for (int i = 0; i < n_in && i < 3; ++i) {
        const int s = in_sizes[i];
        if      (s == Bn * Cc * Ll) x  = d_in[i];
        else if (s == Oo * Rr)      A  = d_in[i];
        else if (s == Rr * KF)      Bm = d_in[i];
    }
    float* out = (float*)d_out;

    const size_t need = (size_t)(KF * Rr + Oo * Rr) * sizeof(float);  // 90112 B
    if (ws_size >= need) {
        float* Bt  = (float*)d_ws;
        float* Afp = Bt + KF * Rr;
        prep_kernel<<<dim3((KF * Rr + 255) / 256), 256, 0, stream>>>(A, Bm, Bt, Afp);
        fused_big<<<dim3(Hh, Bn), 512, 0, stream>>>(x, Bt, Afp, out);
    } else {
        fused_fallback<<<dim3((Bn * Ll) / 256), 256, 0, stream>>>(x, A, Bm, out);
    }
}

// Round 2
// 120.602 us; speedup vs baseline: 1.1465x; 1.1465x over previous
//
#include <hip/hip_runtime.h>
#include <hip/hip_bf16.h>

// LoRA-factored 3x3 conv. out fp32. Input dtypes runtime-detected.
// x: [16,128,56,56], A: [256,16], B: [16,1152] -> out: [16,256,56,56]
// R6: HB=2 output rows per block. Same 72 B-floats/channel now feed 144 FMAs
// (2 rows x 3dh x 3dw x 8 ranks) -> scalar-cache B traffic per row halves,
// x loads per pixel 3 -> 2, per-iteration FMA work (~288cy) now covers the
// s_load latency (~250cy). Grid 448 blocks, 2 blocks/CU -> fully resident,
// one round, no tail. Shifted-accumulator (R5) kept: lane loads only its own
// pixel; dw taps recombined once at the end via __shfl.

#define Bn 16
#define Cc 128
#define Hh 56
#define Ww 56
#define Ll (Hh * Ww)      // 3136
#define Rr 16
#define Oo 256
#define KF (Cc * 9)       // 1152
#define HB 2              // output rows per block

__device__ __forceinline__ float bf16_bits(unsigned short u) {
    return __uint_as_float(((unsigned)u) << 16);
}

template<bool BF>
__device__ __forceinline__ float ld(const void* __restrict__ p, size_t i) {
    if constexpr (BF) return bf16_bits(((const unsigned short*)p)[i]);
    else              return ((const float*)p)[i];
}

// bf16-packed: bits14..7 of each dword = a bf16 exponent (~[96,144]) -> 32/32.
// fp32: uniform mantissa bits -> ~6/32. Threshold 20. (Proven R3.)
__device__ __forceinline__ bool detect_bf16(const void* __restrict__ p) {
    const unsigned* w = (const unsigned*)p;
    int c = 0;
#pragma unroll
    for (int i = 0; i < 32; ++i) {
        const unsigned e = (w[i] >> 7) & 0xFFu;
        c += (e >= 96u && e <= 144u) ? 1 : 0;
    }
    return c >= 20;
}

// ---- prep: Bt[k][r] = B[r][k] as fp32 (k = c*9+i), Afp[o][r] = A[o][r] fp32.
__global__ __launch_bounds__(256) void prep_kernel(
    const void* __restrict__ A, const void* __restrict__ Bm,
    float* __restrict__ Bt, float* __restrict__ Afp)
{
    const bool ab = detect_bf16(A);
    const bool bb = detect_bf16(Bm);
    const int i = blockIdx.x * 256 + threadIdx.x;
    if (i < KF * Rr) {
        const int k = i >> 4, r = i & 15;
        Bt[i] = bb ? bf16_bits(((const unsigned short*)Bm)[r * KF + k])
                   : ((const float*)Bm)[r * KF + k];
    }
    if (i < Oo * Rr) {
        Afp[i] = ab ? bf16_bits(((const unsigned short*)A)[i])
                    : ((const float*)A)[i];
    }
}

// ---- main: one block = (b, rows h0..h0+1). 8 waves = 4 ch-slices x 2 rank-halves.
template<bool XB>
__device__ __forceinline__ void main_body(
    const void* __restrict__ x,
    const float* __restrict__ Bt,
    const float* __restrict__ Afp,
    float* __restrict__ out,
    float (* __restrict__ part)[4][Rr][64],   // [HB][4][16][64]
    float (* __restrict__ tmp2)[64][17])      // [HB][64][17]
{
    const int tid  = threadIdx.x;
    const int lane = tid & 63;                                  // w coordinate
    const int wv   = __builtin_amdgcn_readfirstlane(tid >> 6);  // wave 0..7 (SGPR)
    const int cs   = wv & 3;    // channel slice: channels cs*32 .. +32
    const int rh   = wv >> 2;   // rank half: ranks rh*8 .. +8
    const int h0   = blockIdx.x * HB;
    const int b    = blockIdx.y;
    const int w    = lane;
    const bool wok = (w < Ww);
    const int  wcl = wok ? w : (Ww - 1);   // clamp lanes 56..63 (garbage, masked)

    // a[row][dw][rank]: shifted accumulators, recombined at the end.
    float a[HB][3][8];
#pragma unroll
    for (int row = 0; row < HB; ++row)
#pragma unroll
        for (int dw = 0; dw < 3; ++dw)
#pragma unroll
            for (int j = 0; j < 8; ++j) a[row][dw][j] = 0.f;

    const size_t xbase = (size_t)b * Cc * Ll + (size_t)(cs * 32) * Ll;
    const float* btb   = Bt + (size_t)(cs * 32 * 9) * Rr + rh * 8;

    // rows needed: h0-1 .. h0+HB. validity is block-uniform -> SGPR selects.
    size_t rowb[HB + 2];
    bool   hv[HB + 2];
#pragma unroll
    for (int rr = 0; rr < HB + 2; ++rr) {
        const int hh  = h0 - 1 + rr;
        hv[rr] = (hh >= 0) & (hh < Hh);
        const int hcl = hv[rr] ? hh : (hh < 0 ? 0 : Hh - 1);
        rowb[rr] = xbase + (size_t)(hcl * Ww) + (size_t)wcl;
    }

    for (int cc = 0; cc < 32; ++cc) {
        const size_t coff = (size_t)cc * Ll;
        // 4 independent loads: uniform SGPR base + constant lane offset.
        float xv[HB + 2];
#pragma unroll
        for (int rr = 0; rr < HB + 2; ++rr) {
            const float v = ld<XB>(x, rowb[rr] + coff);
            xv[rr] = hv[rr] ? v : 0.f;
        }
        const float* bt = btb + (size_t)(cc * 9) * Rr;
#pragma unroll
        for (int dh = 0; dh < 3; ++dh) {
            const float x0 = xv[dh];
            const float x1 = xv[dh + 1];
#pragma unroll
            for (int dw = 0; dw < 3; ++dw) {
                const float* bp = bt + (size_t)(dh * 3 + dw) * Rr;
#pragma unroll
                for (int j = 0; j < 8; ++j) {
                    const float bv = bp[j];       // SGPR (uniform) -> s_load_dwordx8
                    a[0][dw][j] += bv * x0;
                    a[1][dw][j] += bv * x1;
                }
            }
        }
    }

    // horizontal recombine (once): out[w] = a1[w] + a0[w-1] + a2[w+1]
#pragma unroll
    for (int row = 0; row < HB; ++row)
#pragma unroll
    for (int j = 0; j < 8; ++j) {
        const float up = __shfl(a[row][0][j], w - 1);
        const float dn = __shfl(a[row][2][j], w + 1);
        float s = a[row][1][j];
        s += (w > 0)      ? up : 0.f;
        s += (w < Ww - 1) ? dn : 0.f;
        part[row][cs][rh * 8 + j][lane] = s;
    }
    __syncthreads();

    // cross-wave reduction: 4 channel-slices -> tmp2[row][px][r]
    {
        const int px = tid & 63;
        const int rr = (tid >> 6) & 7;   // 0..7
#pragma unroll
        for (int row = 0; row < HB; ++row)
#pragma unroll
        for (int t = 0; t < 2; ++t) {
            const int r = rr + t * 8;
            tmp2[row][px][r] = part[row][0][r][px] + part[row][1][r][px]
                             + part[row][2][r][px] + part[row][3][r][px];
        }
    }
    __syncthreads();

    // stage 2: wave wv emits output channels wv*32 .. +32, both rows.
    float tv[HB][Rr];
#pragma unroll
    for (int row = 0; row < HB; ++row)
#pragma unroll
        for (int r = 0; r < Rr; ++r) tv[row][r] = tmp2[row][lane][r];

    const size_t obase = (size_t)b * Oo * Ll + (size_t)(h0 * Ww) + (size_t)w;
#pragma unroll 4
    for (int j = 0; j < 32; ++j) {
        const int o = wv * 32 + j;
        const float* Ao = Afp + (size_t)o * Rr;   // uniform -> s_load
        float s0 = 0.f, s1 = 0.f;
#pragma unroll
        for (int r = 0; r < Rr; ++r) {
            const float av = Ao[r];
            s0 += av * tv[0][r];
            s1 += av * tv[1][r];
        }
        if (wok) {
            out[obase + (size_t)o * Ll]      = s0;
            out[obase + (size_t)o * Ll + Ww] = s1;
        }
    }
}

__global__ __launch_bounds__(512, 4) void fused_big(
    const void* __restrict__ x,
    const float* __restrict__ Bt,
    const float* __restrict__ Afp,
    float* __restrict__ out)
{
    __shared__ float part[HB][4][Rr][64];   // 32 KB
    __shared__ float tmp2[HB][64][17];      // 8.7 KB
    if (detect_bf16(x)) main_body<true >(x, Bt, Afp, out, part, tmp2);
    else                main_body<false>(x, Bt, Afp, out, part, tmp2);
}

// ---- fallback (ws too small): slow but correct, no workspace.
__global__ __launch_bounds__(256) void fused_fallback(
    const void* __restrict__ x, const void* __restrict__ A,
    const void* __restrict__ Bm, float* __restrict__ out)
{
    const bool xb = detect_bf16(x);
    const bool ab = detect_bf16(A);
    const bool bb = detect_bf16(Bm);
    const int gid = blockIdx.x * 256 + threadIdx.x;
    const int b = gid / Ll;
    const int l = gid - b * Ll;
    const int h = l / Ww, w = l - h * Ww;
    float acc[Rr];
#pragma unroll
    for (int r = 0; r < Rr; ++r) acc[r] = 0.f;
    const size_t xbase = (size_t)b * Cc * Ll;
    for (int c = 0; c < Cc; ++c) {
        const size_t xc = xbase + (size_t)c * Ll;
        float xv[9];
#pragma unroll
        for (int dh = 0; dh < 3; ++dh) {
            const int hh = h + dh - 1;
            const bool hok = (hh >= 0) & (hh < Hh);
#pragma unroll
            for (int dw = 0; dw < 3; ++dw) {
                const int ww = w + dw - 1;
                const bool ok = hok & (ww >= 0) & (ww < Ww);
                const size_t idx = xc + (size_t)(hh * Ww + ww);
                xv[dh*3+dw] = ok ? (xb ? bf16_bits(((const unsigned short*)x)[idx])
                                       : ((const float*)x)[idx]) : 0.f;
            }
        }
#pragma unroll
        for (int r = 0; r < Rr; ++r) {
            const size_t bo = (size_t)r * KF + (size_t)c * 9;
            float s = acc[r];
#pragma unroll
            for (int i = 0; i < 9; ++i)
                s += (bb ? bf16_bits(((const unsigned short*)Bm)[bo+i])
                         : ((const float*)Bm)[bo+i]) * xv[i];
            acc[r] = s;
        }
    }
    const size_t obase = (size_t)b * Oo * Ll + (size_t)l;
    for (int o = 0; o < Oo; ++o) {
        float s = 0.f;
#pragma unroll
        for (int r = 0; r < Rr; ++r)
            s += (ab ? bf16_bits(((const unsigned short*)A)[o*Rr+r])
                     : ((const float*)A)[o*Rr+r]) * acc[r];
        out[obase + (size_t)o * Ll] = s;
    }
}

extern "C" void kernel_launch(void* const* d_in, const int* in_sizes, int n_in,
                              void* d_out, int out_size, void* d_ws, size_t ws_size,
                              hipStream_t stream) {
    const void* x  = d_in[0];
    const void* A  = d_in[1];
    const void* Bm = d_in[2];
    for (int i = 0; i < n_in && i < 3; ++i) {
        const int s = in_sizes[i];
        if      (s == Bn * Cc * Ll) x  = d_in[i];
        else if (s == Oo * Rr)      A  = d_in[i];
        else if (s == Rr * KF)      Bm = d_in[i];
    }
    float* out = (float*)d_out;

    const size_t need = (size_t)(KF * Rr + Oo * Rr) * sizeof(float);  // 90112 B
    if (ws_size >= need) {
        float* Bt  = (float*)d_ws;
        float* Afp = Bt + KF * Rr;
        prep_kernel<<<dim3((KF * Rr + 255) / 256), 256, 0, stream>>>(A, Bm, Bt, Afp);
        fused_big<<<dim3(Hh / HB, Bn), 512, 0, stream>>>(x, Bt, Afp, out);
    } else {
        fused_fallback<<<dim3((Bn * Ll) / 256), 256, 0, stream>>>(x, A, Bm, out);
    }
}